// Round 5
// baseline (541.828 us; speedup 1.0000x reference)
//
#include <hip/hip_runtime.h>

#define BATCH 8
#define SEQ   2048
#define DIM   1024   // D == H == 1024

typedef __attribute__((ext_vector_type(8)))  short short8;
typedef __attribute__((ext_vector_type(4)))  short short4v;
typedef __attribute__((ext_vector_type(4)))  float floatx4;
typedef __attribute__((ext_vector_type(16))) float floatx16;

__device__ __forceinline__ unsigned short f32_to_bf16(float f) {
    union { float f; unsigned int u; } x; x.f = f;
    unsigned int r = x.u + 0x7fffu + ((x.u >> 16) & 1u);
    return (unsigned short)(r >> 16);
}

__device__ __forceinline__ float bf16_to_f32(unsigned short h) {
    union { unsigned int u; float f; } x; x.u = ((unsigned int)h) << 16;
    return x.f;
}

// async 16B/lane global->LDS. LDS base wave-uniform; HW scatters lane i at base+16*i.
__device__ __forceinline__ void async_load16(const void* g, void* l) {
    __builtin_amdgcn_global_load_lds(
        (const __attribute__((address_space(1))) void*)g,
        (__attribute__((address_space(3))) void*)l, 16, 0, 0);
}

// ---------------------------------------------------------------------------
// GEMM core: C = A @ B^T (+bias) * scale on a 256x128 tile, 512 threads
// (8 waves, 4 row-bands x 2 col-bands), each wave 64x64 via 2x2
// v_mfma_f32_32x32x16_bf16.  BK=64, single-buffered LDS (48 KB -> 3 blocks/CU,
// 24 waves/CU), XOR-swizzled staging for conflict-managed ds_read_b128.
// ---------------------------------------------------------------------------
template<bool C_BF16, bool BIAS, bool SCATTER>
__device__ __forceinline__ void gemm_core(
    const unsigned short* __restrict__ Abase,   // tile row0 base, row stride K
    const unsigned short* __restrict__ Bbase,   // tile col0 base, row stride K
    void* __restrict__ Cbase,                   // batch base (element units)
    const float* __restrict__ bias,
    int N, int K, int row0, int col0, float scale,
    int climit, const int* __restrict__ ridx)
{
    __shared__ unsigned short As[256 * 64];   // 32 KB
    __shared__ unsigned short Bs[128 * 64];   // 16 KB

    const int tid  = threadIdx.x;
    const int lane = tid & 63;
    const int wave = tid >> 6;        // 0..7
    const int wm   = wave >> 1;       // 0..3 (row band)
    const int wn   = wave & 1;        // 0..1 (col band)
    const int l31  = lane & 31;
    const int half = lane >> 5;       // 0..1
    const int x7   = lane & 7;

    // staging: one async chunk = 1KB = 8 rows x 128B. lane i -> row sr=i>>3,
    // LDS slot i&7; global k-chunk sq = (i&7)^sr (XOR swizzle, in shorts*8)
    const int sr = lane >> 3;                  // 0..7
    const int sq = ((lane & 7) ^ sr) * 8;      // shorts

    const unsigned short* aptr[4];
    const unsigned short* bptr[2];
#pragma unroll
    for (int c = 0; c < 4; ++c) {
        const int r = (wave * 4 + c) * 8 + sr;   // 0..255
        aptr[c] = Abase + (long)r * K + sq;
    }
#pragma unroll
    for (int c = 0; c < 2; ++c) {
        const int r = (wave * 2 + c) * 8 + sr;   // 0..127
        bptr[c] = Bbase + (long)r * K + sq;
    }

    floatx16 acc[2][2];
#pragma unroll
    for (int a = 0; a < 2; ++a)
#pragma unroll
        for (int b = 0; b < 2; ++b)
#pragma unroll
            for (int r = 0; r < 16; ++r) acc[a][b][r] = 0.f;

    // fragment row bases (shorts): row stride 64
    const int raf[2] = { (wm * 64 +  0 + l31) * 64, (wm * 64 + 32 + l31) * 64 };
    const int rbf[2] = { (wn * 64 +  0 + l31) * 64, (wn * 64 + 32 + l31) * 64 };

    for (int kt = 0; kt < K; kt += 64) {
#pragma unroll
        for (int c = 0; c < 4; ++c)
            async_load16(aptr[c] + kt, As + (wave * 4 + c) * 512);
#pragma unroll
        for (int c = 0; c < 2; ++c)
            async_load16(bptr[c] + kt, Bs + (wave * 2 + c) * 512);
        __syncthreads();

#pragma unroll
        for (int ks = 0; ks < 4; ++ks) {
            const int sw = ((ks * 2 + half) ^ x7) << 3;   // swizzled 16B slot (shorts)
            short8 af[2], bf[2];
#pragma unroll
            for (int t = 0; t < 2; ++t) {
                af[t] = *(const short8*)(As + raf[t] + sw);
                bf[t] = *(const short8*)(Bs + rbf[t] + sw);
            }
#pragma unroll
            for (int tm = 0; tm < 2; ++tm)
#pragma unroll
                for (int tn = 0; tn < 2; ++tn)
                    acc[tm][tn] = __builtin_amdgcn_mfma_f32_32x32x16_bf16(
                        af[tm], bf[tn], acc[tm][tn], 0, 0, 0);
        }
        __syncthreads();
    }

    // epilogue: 32x32 C/D layout col=lane&31, row=(reg&3)+8*(reg>>2)+4*(lane>>5)
#pragma unroll
    for (int tn = 0; tn < 2; ++tn) {
        const int ccol = col0 + wn * 64 + tn * 32 + l31;
        float bv = 0.f;
        if (BIAS) bv = bias[ccol];
#pragma unroll
        for (int tm = 0; tm < 2; ++tm) {
            const int rbase = row0 + wm * 64 + tm * 32 + 4 * half;
#pragma unroll
            for (int r = 0; r < 16; ++r) {
                const int crow = rbase + (r & 3) + 8 * (r >> 2);
                float v = acc[tm][tn][r] * scale + bv;
                long orow = crow;
                if (SCATTER) {
                    if (crow >= climit) continue;
                    orow = ridx[crow];
                }
                const long ci = orow * (long)N + ccol;
                if (C_BF16) ((unsigned short*)Cbase)[ci] = f32_to_bf16(v);
                else        ((float*)Cbase)[ci] = v;
            }
        }
    }
}

// generic batched wrapper (LIMIT: skip row-blocks past mlim[z]; SCATTER rows)
template<bool C_BF16, bool BIAS, bool LIMIT, bool SCATTER>
__global__ __launch_bounds__(512) void gemm_bt256(
    const unsigned short* __restrict__ A, const unsigned short* __restrict__ Bt,
    void* __restrict__ Cp, const float* __restrict__ bias,
    int N, int K, long sA, long sB, long sC, float scale,
    const int* __restrict__ mlim, const int* __restrict__ cntp,
    const int* __restrict__ idx)
{
    const int z = blockIdx.z;
    const int row0 = blockIdx.x * 256;
    if (LIMIT && row0 >= mlim[z]) return;
    const int col0 = blockIdx.y * 128;
    const unsigned short* Abase = A + (long)z * sA + (long)row0 * K;
    const unsigned short* Bbase = Bt + (long)z * sB + (long)col0 * K;
    void* Cbase = C_BF16 ? (void*)((unsigned short*)Cp + (long)z * sC)
                         : (void*)((float*)Cp + (long)z * sC);
    const int climit = SCATTER ? cntp[z] : 0;
    const int* ridx  = SCATTER ? (idx + z * SEQ) : (const int*)nullptr;
    gemm_core<C_BF16, BIAS, SCATTER>(Abase, Bbase, Cbase, bias,
                                     N, K, row0, col0, scale, climit, ridx);
}

// merged projections: z=0..7 -> per-batch compacted q-proj; z=8 -> full k-proj
__global__ __launch_bounds__(512) void gemm_proj(
    const unsigned short* __restrict__ qc, const unsigned short* __restrict__ kbf,
    const unsigned short* __restrict__ Wqt, const unsigned short* __restrict__ Wkt,
    unsigned short* __restrict__ qp, unsigned short* __restrict__ kb,
    const float* __restrict__ bq, const float* __restrict__ bk,
    const int* __restrict__ pcnt)
{
    const int z = blockIdx.z;
    const int row0 = blockIdx.x * 256;
    const int col0 = blockIdx.y * 128;
    const unsigned short* Abase;
    const unsigned short* Bbase;
    unsigned short* Cbase;
    const float* bias;
    if (z < 8) {
        if (row0 >= pcnt[z]) return;
        Abase = qc + (long)z * SEQ * DIM + (long)row0 * DIM;
        Bbase = Wqt + (long)col0 * DIM;
        Cbase = qp + (long)z * SEQ * DIM;
        bias  = bq;
    } else {
        Abase = kbf + (long)row0 * DIM;
        Bbase = Wkt + (long)col0 * DIM;
        Cbase = kb;
        bias  = bk;
    }
    gemm_core<true, true, false>(Abase, Bbase, Cbase, bias,
                                 DIM, DIM, row0, col0, 1.0f, 0, nullptr);
}

// ---------------------------------------------------------------------------
// per-batch compaction: idx[b][0..cnt) = rows with mask>0.5 (ascending),
// pads idx[cnt..SEQ) = 0; cnt[b]; padcnt[b] = round-up-256(cnt).
// ---------------------------------------------------------------------------
__global__ __launch_bounds__(256) void build_idx(
    const float* __restrict__ mask, int* __restrict__ idx,
    int* __restrict__ cnt, int* __restrict__ padcnt)
{
    const int b = blockIdx.x;
    const int t = threadIdx.x;
    const float* mb = mask + b * SEQ;
    int flags[8]; int c = 0;
#pragma unroll
    for (int j = 0; j < 8; ++j) {
        flags[j] = (mb[t * 8 + j] > 0.5f) ? 1 : 0;
        c += flags[j];
    }
    int sc = c;                       // inclusive scan within wave
    for (int o = 1; o < 64; o <<= 1) {
        int v = __shfl_up(sc, o);
        if ((t & 63) >= o) sc += v;
    }
    __shared__ int wtot[4];
    const int lane = t & 63, wave = t >> 6;
    if (lane == 63) wtot[wave] = sc;
    __syncthreads();
    int woff = 0;
    for (int w = 0; w < wave; ++w) woff += wtot[w];
    int p = woff + sc - c;            // exclusive offset
#pragma unroll
    for (int j = 0; j < 8; ++j)
        if (flags[j]) idx[b * SEQ + (p++)] = t * 8 + j;
    __syncthreads();
    const int total = wtot[0] + wtot[1] + wtot[2] + wtot[3];
    if (t == 0) { cnt[b] = total; padcnt[b] = (total + 255) & ~255; }
    for (int q = total + t; q < SEQ; q += 256) idx[b * SEQ + q] = 0;
}

// ---------------------------------------------------------------------------
// gather unmasked input_q rows (f32) -> compacted bf16 rows
// ---------------------------------------------------------------------------
__global__ __launch_bounds__(256) void gather_cvt_q(
    const float* __restrict__ xq, const int* __restrict__ idx,
    const int* __restrict__ padcnt, unsigned short* __restrict__ qc)
{
    const int b = blockIdx.y;
    const int rc = blockIdx.x;
    if (rc >= padcnt[b]) return;
    const int src = idx[b * SEQ + rc];
    const float* s = xq + ((long)b * SEQ + src) * DIM + threadIdx.x * 4;
    unsigned short* d = qc + ((long)b * SEQ + rc) * DIM + threadIdx.x * 4;
    floatx4 v = *(const floatx4*)s;
    short4v w;
#pragma unroll
    for (int j = 0; j < 4; ++j) w[j] = (short)f32_to_bf16(v[j]);
    *(short4v*)d = w;
}

// ---------------------------------------------------------------------------
// fused: kbf = bf16(input_k)  AND  mavg += masked column partial sums.
// ---------------------------------------------------------------------------
__global__ __launch_bounds__(256) void prep_k(
    const float* __restrict__ xk, const float* __restrict__ mask,
    unsigned short* __restrict__ kbf, float* __restrict__ mavg)
{
    const int b = blockIdx.x;
    const int d = blockIdx.y * 256 + threadIdx.x;
    const int j0 = blockIdx.z * 256;
    const float* xb = xk + (long)b * SEQ * DIM;
    unsigned short* kb = kbf + (long)b * SEQ * DIM;
    const float* mb = mask + b * SEQ;
    float s = 0.f;
    for (int j = j0; j < j0 + 256; ++j) {
        float mv = mb[j];
        float v  = xb[(long)j * DIM + d];
        kb[(long)j * DIM + d] = f32_to_bf16(v);
        s += (mv <= 0.5f) ? v : 0.f;
    }
    atomicAdd(&mavg[b * DIM + d], s);
}

// ---------------------------------------------------------------------------
// transpose + f32->bf16:  src R x C (row-major, f32) -> dst C x R (bf16)
// ---------------------------------------------------------------------------
__global__ __launch_bounds__(256) void transpose_cvt(
    const float* __restrict__ src, unsigned short* __restrict__ dst,
    int R, int C, long sstride, long dstride)
{
    __shared__ float tile[32][33];
    const long sbase = (long)blockIdx.z * sstride;
    const long dbase = (long)blockIdx.z * dstride;
    const int c0 = blockIdx.x * 32;
    const int r0 = blockIdx.y * 32;
    const int tx = threadIdx.x & 31, ty = threadIdx.x >> 5;   // ty 0..7
#pragma unroll
    for (int i = 0; i < 32; i += 8)
        tile[ty + i][tx] = src[sbase + (long)(r0 + ty + i) * C + c0 + tx];
    __syncthreads();
#pragma unroll
    for (int i = 0; i < 32; i += 8)
        dst[dbase + (long)(c0 + ty + i) * R + r0 + tx] = f32_to_bf16(tile[tx][ty + i]);
}

// ---------------------------------------------------------------------------
// in-place row softmax over 2048 bf16 scores; one block per compacted row
// ---------------------------------------------------------------------------
__global__ __launch_bounds__(256) void softmax_rows(
    unsigned short* __restrict__ S, const int* __restrict__ padcnt)
{
    const int b = blockIdx.x >> 11, rc = blockIdx.x & 2047;
    if (rc >= padcnt[b]) return;
    const long base = (long)blockIdx.x * SEQ + threadIdx.x * 8;
    const int lane = threadIdx.x & 63, wave = threadIdx.x >> 6;
    __shared__ float rbuf[8];

    short8 v = *(const short8*)(S + base);
    float x[8];
#pragma unroll
    for (int j = 0; j < 8; ++j) x[j] = bf16_to_f32((unsigned short)v[j]);

    float m = x[0];
#pragma unroll
    for (int j = 1; j < 8; ++j) m = fmaxf(m, x[j]);
    for (int o = 32; o; o >>= 1) m = fmaxf(m, __shfl_xor(m, o));
    if (lane == 0) rbuf[wave] = m;
    __syncthreads();
    m = fmaxf(fmaxf(rbuf[0], rbuf[1]), fmaxf(rbuf[2], rbuf[3]));

    float e[8], s = 0.f;
#pragma unroll
    for (int j = 0; j < 8; ++j) { e[j] = __expf(x[j] - m); s += e[j]; }
    for (int o = 32; o; o >>= 1) s += __shfl_xor(s, o);
    if (lane == 0) rbuf[4 + wave] = s;
    __syncthreads();
    s = rbuf[4] + rbuf[5] + rbuf[6] + rbuf[7];
    const float inv = 1.0f / s;

    short8 o8;
#pragma unroll
    for (int j = 0; j < 8; ++j) o8[j] = (short)f32_to_bf16(e[j] * inv);
    *(short8*)(S + base) = o8;
}

// ---------------------------------------------------------------------------
// rows with mask<=0.5: out[b,i,:] = mavg[b,:]/masked_count  (exact fp32 path)
// ---------------------------------------------------------------------------
__global__ __launch_bounds__(256) void overwrite_masked(
    float* __restrict__ out, const float* __restrict__ mask,
    const float* __restrict__ mavg, const int* __restrict__ cnt)
{
    const int bid = blockIdx.x;            // b*SEQ + i
    const int b = bid >> 11;
    if (mask[bid] > 0.5f) return;
    const float inv = 1.0f / (float)(SEQ - cnt[b]);
    const long obase = (long)bid * DIM;
    const float* mv = mavg + b * DIM;
    for (int d = threadIdx.x; d < DIM; d += 256)
        out[obase + d] = mv[d] * inv;
}

extern "C" void kernel_launch(void* const* d_in, const int* in_sizes, int n_in,
                              void* d_out, int out_size, void* d_ws, size_t ws_size,
                              hipStream_t stream) {
    (void)in_sizes; (void)n_in; (void)out_size;
    const float* input_q = (const float*)d_in[0];
    const float* input_k = (const float*)d_in[1];
    const float* k_mask  = (const float*)d_in[2];
    const float* Wq      = (const float*)d_in[3];
    const float* bq      = (const float*)d_in[4];
    const float* Wk      = (const float*)d_in[5];
    const float* bk      = (const float*)d_in[6];
    float* out = (float*)d_out;

    // Workspace map. qc/kbf alias S (dead before scores GEMM writes S).
    char* ws = (char*)d_ws;
    unsigned short* qc   = (unsigned short*)(ws);                 // 32MB (aliases S lo)
    unsigned short* kbf  = (unsigned short*)(ws + 33554432);      // 32MB (aliases S hi)
    unsigned short* S    = (unsigned short*)(ws);                 // 64MB
    unsigned short* qp   = (unsigned short*)(ws + 67108864);      // 32MB
    unsigned short* kb   = (unsigned short*)(ws + 100663296);     // 32MB
    unsigned short* Vt   = (unsigned short*)(ws + 134217728);     // 32MB
    unsigned short* Wqt  = (unsigned short*)(ws + 167772160);     // 2MB
    unsigned short* Wkt  = (unsigned short*)(ws + 169869312);     // 2MB
    float*          mavg = (float*)(ws + 171966464);              // 32KB
    int*            idx  = (int*)(ws + 171999232);                // 64KB
    int*            cnts = (int*)(ws + 172064768);                // 32B
    int*            pcnt = (int*)(ws + 172064800);                // 32B
    if (ws_size < 172064832) return;

    hipMemsetAsync(mavg, 0, BATCH * DIM * sizeof(float), stream);

    build_idx<<<BATCH, 256, 0, stream>>>(k_mask, idx, cnts, pcnt);
    gather_cvt_q<<<dim3(SEQ, BATCH), 256, 0, stream>>>(input_q, idx, pcnt, qc);
    prep_k<<<dim3(BATCH, DIM / 256, SEQ / 256), 256, 0, stream>>>(input_k, k_mask, kbf, mavg);
    transpose_cvt<<<dim3(32, 32, 1), 256, 0, stream>>>(Wq, Wqt, DIM, DIM, 0, 0);
    transpose_cvt<<<dim3(32, 32, 1), 256, 0, stream>>>(Wk, Wkt, DIM, DIM, 0, 0);
    transpose_cvt<<<dim3(32, 64, BATCH), 256, 0, stream>>>(input_k, Vt, SEQ, DIM,
                                                           (long)SEQ * DIM, (long)DIM * SEQ);

    // merged q-proj (z=0..7, compacted) + k-proj (z=8, full 16384 rows)
    gemm_proj<<<dim3(64, 8, 9), 512, 0, stream>>>(qc, kbf, Wqt, Wkt, qp, kb, bq, bk, pcnt);

    // scores: per batch S[rc,:] = qp[rc] @ k^T / 32 -> bf16 (compacted rows)
    gemm_bt256<true, false, true, false><<<dim3(8, 16, BATCH), 512, 0, stream>>>(
        qp, kb, S, nullptr, SEQ, DIM,
        (long)SEQ * DIM, (long)SEQ * DIM, (long)SEQ * SEQ, 0.03125f, pcnt, nullptr, nullptr);

    softmax_rows<<<BATCH * SEQ, 256, 0, stream>>>(S, pcnt);

    // out rows (scattered): per batch P @ V with row map idx
    gemm_bt256<false, false, true, true><<<dim3(8, 8, BATCH), 512, 0, stream>>>(
        S, Vt, out, nullptr, DIM, SEQ,
        (long)SEQ * SEQ, (long)DIM * SEQ, (long)SEQ * DIM, 1.0f, pcnt, cnts, idx);

    overwrite_masked<<<BATCH * SEQ, 256, 0, stream>>>(out, k_mask, mavg, cnts);
}

// Round 6
// 493.941 us; speedup vs baseline: 1.0969x; 1.0969x over previous
//
#include <hip/hip_runtime.h>

#define BATCH 8
#define SEQ   2048
#define DIM   1024   // D == H == 1024

typedef __attribute__((ext_vector_type(8)))  short short8;
typedef __attribute__((ext_vector_type(4)))  short short4v;
typedef __attribute__((ext_vector_type(4)))  float floatx4;
typedef __attribute__((ext_vector_type(16))) float floatx16;

__device__ __forceinline__ unsigned short f32_to_bf16(float f) {
    union { float f; unsigned int u; } x; x.f = f;
    unsigned int r = x.u + 0x7fffu + ((x.u >> 16) & 1u);
    return (unsigned short)(r >> 16);
}

__device__ __forceinline__ float bf16_to_f32(unsigned short h) {
    union { unsigned int u; float f; } x; x.u = ((unsigned int)h) << 16;
    return x.f;
}

// async 16B/lane global->LDS. LDS base wave-uniform; HW scatters lane i at base+16*i.
__device__ __forceinline__ void async_load16(const void* g, void* l) {
    __builtin_amdgcn_global_load_lds(
        (const __attribute__((address_space(1))) void*)g,
        (__attribute__((address_space(3))) void*)l, 16, 0, 0);
}

// ---------------------------------------------------------------------------
// per-batch compaction: idx[b][0..cnt) = rows with mask>0.5 (ascending),
// pads idx[cnt..SEQ) = 0; cnt[b]; padcnt[b] = round-up-128(cnt).
// ---------------------------------------------------------------------------
__global__ __launch_bounds__(256) void build_idx(
    const float* __restrict__ mask, int* __restrict__ idx,
    int* __restrict__ cnt, int* __restrict__ padcnt)
{
    const int b = blockIdx.x;
    const int t = threadIdx.x;
    const float* mb = mask + b * SEQ;
    int flags[8]; int c = 0;
#pragma unroll
    for (int j = 0; j < 8; ++j) {
        flags[j] = (mb[t * 8 + j] > 0.5f) ? 1 : 0;
        c += flags[j];
    }
    int sc = c;                       // inclusive scan within wave
    for (int o = 1; o < 64; o <<= 1) {
        int v = __shfl_up(sc, o);
        if ((t & 63) >= o) sc += v;
    }
    __shared__ int wtot[4];
    const int lane = t & 63, wave = t >> 6;
    if (lane == 63) wtot[wave] = sc;
    __syncthreads();
    int woff = 0;
    for (int w = 0; w < wave; ++w) woff += wtot[w];
    int p = woff + sc - c;            // exclusive offset
#pragma unroll
    for (int j = 0; j < 8; ++j)
        if (flags[j]) idx[b * SEQ + (p++)] = t * 8 + j;
    __syncthreads();
    const int total = wtot[0] + wtot[1] + wtot[2] + wtot[3];
    if (t == 0) { cnt[b] = total; padcnt[b] = (total + 127) & ~127; }
    for (int q = total + t; q < SEQ; q += 256) idx[b * SEQ + q] = 0;
}

// ---------------------------------------------------------------------------
// gather unmasked input_q rows (f32) -> compacted bf16 rows
// ---------------------------------------------------------------------------
__global__ __launch_bounds__(256) void gather_cvt_q(
    const float* __restrict__ xq, const int* __restrict__ idx,
    const int* __restrict__ padcnt, unsigned short* __restrict__ qc)
{
    const int b = blockIdx.y;
    const int rc = blockIdx.x;
    if (rc >= padcnt[b]) return;
    const int src = idx[b * SEQ + rc];
    const float* s = xq + ((long)b * SEQ + src) * DIM + threadIdx.x * 4;
    unsigned short* d = qc + ((long)b * SEQ + rc) * DIM + threadIdx.x * 4;
    floatx4 v = *(const floatx4*)s;
    short4v w;
#pragma unroll
    for (int j = 0; j < 4; ++j) w[j] = (short)f32_to_bf16(v[j]);
    *(short4v*)d = w;
}

// ---------------------------------------------------------------------------
// fused: kbf = bf16(input_k)  AND  mavg += masked column partial sums.
// ---------------------------------------------------------------------------
__global__ __launch_bounds__(256) void prep_k(
    const float* __restrict__ xk, const float* __restrict__ mask,
    unsigned short* __restrict__ kbf, float* __restrict__ mavg)
{
    const int b = blockIdx.x;
    const int d = blockIdx.y * 256 + threadIdx.x;
    const int j0 = blockIdx.z * 256;
    const float* xb = xk + (long)b * SEQ * DIM;
    unsigned short* kb = kbf + (long)b * SEQ * DIM;
    const float* mb = mask + b * SEQ;
    float s = 0.f;
    for (int j = j0; j < j0 + 256; ++j) {
        float mv = mb[j];
        float v  = xb[(long)j * DIM + d];
        kb[(long)j * DIM + d] = f32_to_bf16(v);
        s += (mv <= 0.5f) ? v : 0.f;
    }
    atomicAdd(&mavg[b * DIM + d], s);
}

// ---------------------------------------------------------------------------
// f32 -> bf16 bulk convert, 8 elems/thread
// ---------------------------------------------------------------------------
__global__ __launch_bounds__(256) void cvt_bf16(
    const float* __restrict__ src, unsigned short* __restrict__ dst)
{
    const long i = ((long)blockIdx.x * 256 + threadIdx.x) * 8;
    floatx4 v0 = *(const floatx4*)(src + i);
    floatx4 v1 = *(const floatx4*)(src + i + 4);
    short8 w;
#pragma unroll
    for (int j = 0; j < 4; ++j) w[j]     = (short)f32_to_bf16(v0[j]);
#pragma unroll
    for (int j = 0; j < 4; ++j) w[4 + j] = (short)f32_to_bf16(v1[j]);
    *(short8*)(dst + i) = w;
}

// ---------------------------------------------------------------------------
// g0[d] = sum_h bq[h] * Wk[d,h]   (Wk row-major (D,H)); one block per d
// ---------------------------------------------------------------------------
__global__ __launch_bounds__(256) void proj_bias(
    const float* __restrict__ bq, const float* __restrict__ Wk, float* __restrict__ g0)
{
    const int n = blockIdx.x;
    const int t = threadIdx.x;
    float s = 0.f;
    for (int h = t; h < DIM; h += 256) s += bq[h] * Wk[(long)n * DIM + h];
    for (int o = 32; o; o >>= 1) s += __shfl_xor(s, o);
    __shared__ float r[4];
    if ((t & 63) == 0) r[t >> 6] = s;
    __syncthreads();
    if (t == 0) g0[n] = r[0] + r[1] + r[2] + r[3];
}

// ---------------------------------------------------------------------------
// C = A @ B^T (+bias) * scale.  A: MxK bf16, Bt: NxK bf16, C: MxN (bf16|f32).
// 128x128 block tile, BK=64, 256 threads (4 waves 2x2), each wave 64x64 via
// 2x2 v_mfma_f32_32x32x16_bf16.  XOR-swizzled LDS staging, single buffer
// (32 KB -> up to 5 blocks/CU).
// LIMIT: skip row-blocks past mlim[z].  SCATTER: row -> idx[z][row], < cnt[z].
// ---------------------------------------------------------------------------
template<bool C_BF16, bool BIAS, bool LIMIT, bool SCATTER>
__global__ __launch_bounds__(256) void gemm_bt(
    const unsigned short* __restrict__ A, const unsigned short* __restrict__ Bt,
    void* __restrict__ Cp, const float* __restrict__ bias,
    int N, int K, long sA, long sB, long sC, float scale,
    const int* __restrict__ mlim, const int* __restrict__ cntp,
    const int* __restrict__ idx)
{
    const int row0 = blockIdx.x * 128;
    if (LIMIT && row0 >= mlim[blockIdx.z]) return;

    __shared__ unsigned short As[128 * 64];
    __shared__ unsigned short Bs[128 * 64];

    const int tid  = threadIdx.x;
    const int lane = tid & 63;
    const int wave = tid >> 6;
    const int wm   = wave >> 1;       // 0..1
    const int wn   = wave & 1;        // 0..1
    const int l31  = lane & 31;
    const int half = lane >> 5;       // 0..1
    const int x7   = lane & 7;
    const int col0 = blockIdx.y * 128;
    const long zA = (long)blockIdx.z * sA;
    const long zB = (long)blockIdx.z * sB;
    const long zC = (long)blockIdx.z * sC;

    // staging: one async chunk = 1KB = 8 rows x 128B. lane i -> row sr=i>>3,
    // LDS slot i&7; global k-chunk sq = (i&7)^sr (XOR swizzle, in shorts*8)
    const int sr = lane >> 3;                  // 0..7
    const int sq = ((lane & 7) ^ sr) * 8;      // shorts

    const unsigned short* Abase = A  + zA + (long)row0 * K;
    const unsigned short* Bbase = Bt + zB + (long)col0 * K;
    const unsigned short* aptr[4];
    const unsigned short* bptr[4];
#pragma unroll
    for (int c = 0; c < 4; ++c) {
        const int r = (wave * 4 + c) * 8 + sr;   // 0..127
        aptr[c] = Abase + (long)r * K + sq;
        bptr[c] = Bbase + (long)r * K + sq;
    }

    floatx16 acc[2][2];
#pragma unroll
    for (int a = 0; a < 2; ++a)
#pragma unroll
        for (int b = 0; b < 2; ++b)
#pragma unroll
            for (int r = 0; r < 16; ++r) acc[a][b][r] = 0.f;

    // fragment row bases (shorts): row stride 64
    const int raf[2] = { (wm * 64 +  0 + l31) * 64, (wm * 64 + 32 + l31) * 64 };
    const int rbf[2] = { (wn * 64 +  0 + l31) * 64, (wn * 64 + 32 + l31) * 64 };

    for (int kt = 0; kt < K; kt += 64) {
#pragma unroll
        for (int c = 0; c < 4; ++c) {
            const int chunk = wave * 4 + c;
            async_load16(aptr[c] + kt, As + chunk * 512);
            async_load16(bptr[c] + kt, Bs + chunk * 512);
        }
        __syncthreads();

#pragma unroll
        for (int ks = 0; ks < 4; ++ks) {
            const int sw = ((ks * 2 + half) ^ x7) << 3;   // swizzled 16B slot (shorts)
            short8 af[2], bf[2];
#pragma unroll
            for (int t = 0; t < 2; ++t) {
                af[t] = *(const short8*)(As + raf[t] + sw);
                bf[t] = *(const short8*)(Bs + rbf[t] + sw);
            }
#pragma unroll
            for (int tm = 0; tm < 2; ++tm)
#pragma unroll
                for (int tn = 0; tn < 2; ++tn)
                    acc[tm][tn] = __builtin_amdgcn_mfma_f32_32x32x16_bf16(
                        af[tm], bf[tn], acc[tm][tn], 0, 0, 0);
        }
        __syncthreads();
    }

    // epilogue: 32x32 C/D layout col=lane&31, row=(reg&3)+8*(reg>>2)+4*(lane>>5)
    const int climit = SCATTER ? cntp[blockIdx.z] : 0;
    const int* ridx  = SCATTER ? (idx + blockIdx.z * SEQ) : (const int*)nullptr;
#pragma unroll
    for (int tn = 0; tn < 2; ++tn) {
        const int ccol = col0 + wn * 64 + tn * 32 + l31;
        float bv = 0.f;
        if (BIAS) bv = bias[ccol];
#pragma unroll
        for (int tm = 0; tm < 2; ++tm) {
            const int rbase = row0 + wm * 64 + tm * 32 + 4 * half;
#pragma unroll
            for (int r = 0; r < 16; ++r) {
                const int crow = rbase + (r & 3) + 8 * (r >> 2);
                float v = acc[tm][tn][r] * scale + bv;
                long orow = crow;
                if (SCATTER) {
                    if (crow >= climit) continue;
                    orow = ridx[crow];
                }
                const long ci = zC + orow * (long)N + ccol;
                if (C_BF16) ((unsigned short*)Cp)[ci] = f32_to_bf16(v);
                else        ((float*)Cp)[ci] = v;
            }
        }
    }
}

// ---------------------------------------------------------------------------
// transpose + f32->bf16:  src R x C (row-major, f32) -> dst C x R (bf16)
// ---------------------------------------------------------------------------
__global__ __launch_bounds__(256) void transpose_cvt(
    const float* __restrict__ src, unsigned short* __restrict__ dst,
    int R, int C, long sstride, long dstride)
{
    __shared__ float tile[32][33];
    const long sbase = (long)blockIdx.z * sstride;
    const long dbase = (long)blockIdx.z * dstride;
    const int c0 = blockIdx.x * 32;
    const int r0 = blockIdx.y * 32;
    const int tx = threadIdx.x & 31, ty = threadIdx.x >> 5;   // ty 0..7
#pragma unroll
    for (int i = 0; i < 32; i += 8)
        tile[ty + i][tx] = src[sbase + (long)(r0 + ty + i) * C + c0 + tx];
    __syncthreads();
#pragma unroll
    for (int i = 0; i < 32; i += 8)
        dst[dbase + (long)(c0 + ty + i) * R + r0 + tx] = f32_to_bf16(tile[tx][ty + i]);
}

// ---------------------------------------------------------------------------
// in-place row softmax over 2048 bf16 scores; one block per compacted row
// ---------------------------------------------------------------------------
__global__ __launch_bounds__(256) void softmax_rows(
    unsigned short* __restrict__ S, const int* __restrict__ padcnt)
{
    const int b = blockIdx.x >> 11, rc = blockIdx.x & 2047;
    if (rc >= padcnt[b]) return;
    const long base = (long)blockIdx.x * SEQ + threadIdx.x * 8;
    const int lane = threadIdx.x & 63, wave = threadIdx.x >> 6;
    __shared__ float rbuf[8];

    short8 v = *(const short8*)(S + base);
    float x[8];
#pragma unroll
    for (int j = 0; j < 8; ++j) x[j] = bf16_to_f32((unsigned short)v[j]);

    float m = x[0];
#pragma unroll
    for (int j = 1; j < 8; ++j) m = fmaxf(m, x[j]);
    for (int o = 32; o; o >>= 1) m = fmaxf(m, __shfl_xor(m, o));
    if (lane == 0) rbuf[wave] = m;
    __syncthreads();
    m = fmaxf(fmaxf(rbuf[0], rbuf[1]), fmaxf(rbuf[2], rbuf[3]));

    float e[8], s = 0.f;
#pragma unroll
    for (int j = 0; j < 8; ++j) { e[j] = __expf(x[j] - m); s += e[j]; }
    for (int o = 32; o; o >>= 1) s += __shfl_xor(s, o);
    if (lane == 0) rbuf[4 + wave] = s;
    __syncthreads();
    s = rbuf[4] + rbuf[5] + rbuf[6] + rbuf[7];
    const float inv = 1.0f / s;

    short8 o8;
#pragma unroll
    for (int j = 0; j < 8; ++j) o8[j] = (short)f32_to_bf16(e[j] * inv);
    *(short8*)(S + base) = o8;
}

// ---------------------------------------------------------------------------
// rows with mask<=0.5: out[b,i,:] = mavg[b,:]/masked_count  (exact fp32 path)
// ---------------------------------------------------------------------------
__global__ __launch_bounds__(256) void overwrite_masked(
    float* __restrict__ out, const float* __restrict__ mask,
    const float* __restrict__ mavg, const int* __restrict__ cnt)
{
    const int bid = blockIdx.x;            // b*SEQ + i
    const int b = bid >> 11;
    if (mask[bid] > 0.5f) return;
    const float inv = 1.0f / (float)(SEQ - cnt[b]);
    const long obase = (long)bid * DIM;
    const float* mv = mavg + b * DIM;
    for (int d = threadIdx.x; d < DIM; d += 256)
        out[obase + d] = mv[d] * inv;
}

extern "C" void kernel_launch(void* const* d_in, const int* in_sizes, int n_in,
                              void* d_out, int out_size, void* d_ws, size_t ws_size,
                              hipStream_t stream) {
    (void)in_sizes; (void)n_in; (void)out_size;
    const float* input_q = (const float*)d_in[0];
    const float* input_k = (const float*)d_in[1];
    const float* k_mask  = (const float*)d_in[2];
    const float* Wq      = (const float*)d_in[3];
    const float* bq      = (const float*)d_in[4];
    const float* Wk      = (const float*)d_in[5];
    const float* bk      = (const float*)d_in[6];
    (void)bk;   // bk shifts each score row by a constant -> softmax-invariant
    float* out = (float*)d_out;

    // Workspace map (aliases are sequenced by stream order):
    //   qc   aliases S lo 32MB      (dead once qpp computed, before scores writes S)
    //   Wqb/Wkb alias qpp lo 4MB    (dead once Gt computed, before qpp written)
    char* ws = (char*)d_ws;
    unsigned short* qc   = (unsigned short*)(ws);                 // 32MB
    unsigned short* S    = (unsigned short*)(ws);                 // 64MB
    unsigned short* qpp  = (unsigned short*)(ws + 67108864);      // 32MB
    unsigned short* Wqb  = (unsigned short*)(ws + 67108864);      // 2MB (alias)
    unsigned short* Wkb  = (unsigned short*)(ws + 69206016);      // 2MB (alias)
    unsigned short* kbf  = (unsigned short*)(ws + 100663296);     // 32MB
    unsigned short* Vt   = (unsigned short*)(ws + 134217728);     // 32MB
    unsigned short* Gt   = (unsigned short*)(ws + 167772160);     // 2MB
    float*          g0   = (float*)(ws + 169869312);              // 4KB
    float*          mavg = (float*)(ws + 169873408);              // 32KB
    int*            idx  = (int*)(ws + 169906176);                // 64KB
    int*            cnts = (int*)(ws + 169971712);                // 32B
    int*            pcnt = (int*)(ws + 169971744);                // 32B
    if (ws_size < 169971776) return;

    hipMemsetAsync(mavg, 0, BATCH * DIM * sizeof(float), stream);

    build_idx<<<BATCH, 256, 0, stream>>>(k_mask, idx, cnts, pcnt);
    gather_cvt_q<<<dim3(SEQ, BATCH), 256, 0, stream>>>(input_q, idx, pcnt, qc);
    prep_k<<<dim3(BATCH, DIM / 256, SEQ / 256), 256, 0, stream>>>(input_k, k_mask, kbf, mavg);
    transpose_cvt<<<dim3(32, 64, BATCH), 256, 0, stream>>>(input_k, Vt, SEQ, DIM,
                                                           (long)SEQ * DIM, (long)DIM * SEQ);
    cvt_bf16<<<512, 256, 0, stream>>>(Wq, Wqb);
    cvt_bf16<<<512, 256, 0, stream>>>(Wk, Wkb);
    proj_bias<<<DIM, 256, 0, stream>>>(bq, Wk, g0);

    // Gt[d,e] = sum_h Wk[d,h] * Wq[e,h]   (the combined projection, 1024^3)
    gemm_bt<true, false, false, false><<<dim3(8, 8, 1), 256, 0, stream>>>(
        Wkb, Wqb, Gt, nullptr, DIM, DIM, 0, 0, 0, 1.0f, nullptr, nullptr, nullptr);

    // q''[m,d] = sum_e qc[m,e] * Gt[d,e] + g0[d]   (compacted rows; clobbers Wqb/Wkb)
    gemm_bt<true, true, true, false><<<dim3(16, 8, BATCH), 256, 0, stream>>>(
        qc, Gt, qpp, g0, DIM, DIM,
        (long)SEQ * DIM, 0, (long)SEQ * DIM, 1.0f, pcnt, nullptr, nullptr);

    // scores: S[i,j] = q''[i,:] . kbf[j,:] / 32 -> bf16 (no k-projection!)
    gemm_bt<true, false, true, false><<<dim3(16, 16, BATCH), 256, 0, stream>>>(
        qpp, kbf, S, nullptr, SEQ, DIM,
        (long)SEQ * DIM, (long)SEQ * DIM, (long)SEQ * SEQ, 0.03125f, pcnt, nullptr, nullptr);

    softmax_rows<<<BATCH * SEQ, 256, 0, stream>>>(S, pcnt);

    // out rows (scattered): per batch P @ V with row map idx
    gemm_bt<false, false, true, true><<<dim3(16, 8, BATCH), 256, 0, stream>>>(
        S, Vt, out, nullptr, DIM, SEQ,
        (long)SEQ * SEQ, (long)DIM * SEQ, (long)SEQ * DIM, 1.0f, pcnt, cnts, idx);

    overwrite_masked<<<BATCH * SEQ, 256, 0, stream>>>(out, k_mask, mavg, cnts);
}

// Round 7
// 366.443 us; speedup vs baseline: 1.4786x; 1.3479x over previous
//
#include <hip/hip_runtime.h>

#define BATCH 8
#define SEQ   2048
#define DIM   1024   // D == H == 1024

typedef __attribute__((ext_vector_type(8)))  short short8;
typedef __attribute__((ext_vector_type(4)))  short short4v;
typedef __attribute__((ext_vector_type(4)))  float floatx4;
typedef __attribute__((ext_vector_type(16))) float floatx16;

__device__ __forceinline__ unsigned short f32_to_bf16(float f) {
    union { float f; unsigned int u; } x; x.f = f;
    unsigned int r = x.u + 0x7fffu + ((x.u >> 16) & 1u);
    return (unsigned short)(r >> 16);
}

__device__ __forceinline__ float bf16_to_f32(unsigned short h) {
    union { unsigned int u; float f; } x; x.u = ((unsigned int)h) << 16;
    return x.f;
}

// async 16B/lane global->LDS. LDS base wave-uniform; HW scatters lane i at base+16*i.
__device__ __forceinline__ void async_load16(const void* g, void* l) {
    __builtin_amdgcn_global_load_lds(
        (const __attribute__((address_space(1))) void*)g,
        (__attribute__((address_space(3))) void*)l, 16, 0, 0);
}

// ---------------------------------------------------------------------------
// per-batch compaction: idx[b][0..cnt) = rows with mask>0.5 (ascending),
// pads idx[cnt..SEQ) = 0; cnt[b]; padcnt[b] = round-up-128(cnt).
// ---------------------------------------------------------------------------
__global__ __launch_bounds__(256) void build_idx(
    const float* __restrict__ mask, int* __restrict__ idx,
    int* __restrict__ cnt, int* __restrict__ padcnt)
{
    const int b = blockIdx.x;
    const int t = threadIdx.x;
    const float* mb = mask + b * SEQ;
    int flags[8]; int c = 0;
#pragma unroll
    for (int j = 0; j < 8; ++j) {
        flags[j] = (mb[t * 8 + j] > 0.5f) ? 1 : 0;
        c += flags[j];
    }
    int sc = c;                       // inclusive scan within wave
    for (int o = 1; o < 64; o <<= 1) {
        int v = __shfl_up(sc, o);
        if ((t & 63) >= o) sc += v;
    }
    __shared__ int wtot[4];
    const int lane = t & 63, wave = t >> 6;
    if (lane == 63) wtot[wave] = sc;
    __syncthreads();
    int woff = 0;
    for (int w = 0; w < wave; ++w) woff += wtot[w];
    int p = woff + sc - c;            // exclusive offset
#pragma unroll
    for (int j = 0; j < 8; ++j)
        if (flags[j]) idx[b * SEQ + (p++)] = t * 8 + j;
    __syncthreads();
    const int total = wtot[0] + wtot[1] + wtot[2] + wtot[3];
    if (t == 0) { cnt[b] = total; padcnt[b] = (total + 127) & ~127; }
    for (int q = total + t; q < SEQ; q += 256) idx[b * SEQ + q] = 0;
}

// ---------------------------------------------------------------------------
// gather unmasked input_q rows (f32) -> compacted bf16 rows
// ---------------------------------------------------------------------------
__global__ __launch_bounds__(256) void gather_cvt_q(
    const float* __restrict__ xq, const int* __restrict__ idx,
    const int* __restrict__ padcnt, unsigned short* __restrict__ qc)
{
    const int b = blockIdx.y;
    const int rc = blockIdx.x;
    if (rc >= padcnt[b]) return;
    const int src = idx[b * SEQ + rc];
    const float* s = xq + ((long)b * SEQ + src) * DIM + threadIdx.x * 4;
    unsigned short* d = qc + ((long)b * SEQ + rc) * DIM + threadIdx.x * 4;
    floatx4 v = *(const floatx4*)s;
    short4v w;
#pragma unroll
    for (int j = 0; j < 4; ++j) w[j] = (short)f32_to_bf16(v[j]);
    *(short4v*)d = w;
}

// ---------------------------------------------------------------------------
// fused single pass over input_k:
//   kbf = bf16(input_k)  (straight layout)
//   Vt  = bf16(input_k)^T per batch (DIM x SEQ)
//   mavg += masked column partial sums
// grid (DIM/32, SEQ/32, BATCH), block 256 (32x8)
// ---------------------------------------------------------------------------
__global__ __launch_bounds__(256) void prep_kv(
    const float* __restrict__ xk, const float* __restrict__ mask,
    unsigned short* __restrict__ kbf, unsigned short* __restrict__ Vt,
    float* __restrict__ mavg)
{
    __shared__ float tile[32][33];
    __shared__ float msk[32];
    __shared__ float csum[8][32];
    const int b  = blockIdx.z;
    const int c0 = blockIdx.x * 32;   // dim cols
    const int r0 = blockIdx.y * 32;   // seq rows
    const int tx = threadIdx.x & 31, ty = threadIdx.x >> 5;   // ty 0..7
    const float* xb = xk + (long)b * SEQ * DIM;
    unsigned short* kb = kbf + (long)b * SEQ * DIM;
    unsigned short* vb = Vt + (long)b * DIM * SEQ;

    if (threadIdx.x < 32) msk[threadIdx.x] = mask[b * SEQ + r0 + threadIdx.x];

    float v[4];
#pragma unroll
    for (int i = 0; i < 4; ++i) {
        const int r = ty + i * 8;
        v[i] = xb[(long)(r0 + r) * DIM + c0 + tx];
        tile[r][tx] = v[i];
        kb[(long)(r0 + r) * DIM + c0 + tx] = f32_to_bf16(v[i]);
    }
    __syncthreads();

    float s = 0.f;
#pragma unroll
    for (int i = 0; i < 4; ++i) {
        const int r = ty + i * 8;
        s += (msk[r] <= 0.5f) ? v[i] : 0.f;
    }
    csum[ty][tx] = s;

#pragma unroll
    for (int i = 0; i < 4; ++i) {
        const int c = ty + i * 8;
        vb[(long)(c0 + c) * SEQ + r0 + tx] = f32_to_bf16(tile[tx][c]);
    }
    __syncthreads();
    if (ty == 0) {
        float t = 0.f;
#pragma unroll
        for (int j = 0; j < 8; ++j) t += csum[j][tx];
        atomicAdd(&mavg[b * DIM + c0 + tx], t);
    }
}

// ---------------------------------------------------------------------------
// f32 -> bf16 bulk convert, 8 elems/thread
// ---------------------------------------------------------------------------
__global__ __launch_bounds__(256) void cvt_bf16(
    const float* __restrict__ src, unsigned short* __restrict__ dst)
{
    const long i = ((long)blockIdx.x * 256 + threadIdx.x) * 8;
    floatx4 v0 = *(const floatx4*)(src + i);
    floatx4 v1 = *(const floatx4*)(src + i + 4);
    short8 w;
#pragma unroll
    for (int j = 0; j < 4; ++j) w[j]     = (short)f32_to_bf16(v0[j]);
#pragma unroll
    for (int j = 0; j < 4; ++j) w[4 + j] = (short)f32_to_bf16(v1[j]);
    *(short8*)(dst + i) = w;
}

// ---------------------------------------------------------------------------
// g0[d] = sum_h bq[h] * Wk[d,h]   (Wk row-major (D,H)); one block per d
// ---------------------------------------------------------------------------
__global__ __launch_bounds__(256) void proj_bias(
    const float* __restrict__ bq, const float* __restrict__ Wk, float* __restrict__ g0)
{
    const int n = blockIdx.x;
    const int t = threadIdx.x;
    float s = 0.f;
    for (int h = t; h < DIM; h += 256) s += bq[h] * Wk[(long)n * DIM + h];
    for (int o = 32; o; o >>= 1) s += __shfl_xor(s, o);
    __shared__ float r[4];
    if ((t & 63) == 0) r[t >> 6] = s;
    __syncthreads();
    if (t == 0) g0[n] = r[0] + r[1] + r[2] + r[3];
}

// ---------------------------------------------------------------------------
// C = A @ B^T (+bias) * scale.  A: MxK bf16, Bt: NxK bf16, C: MxN (bf16|f32).
// 128x128 block tile, BK=64, 256 threads (4 waves 2x2), each wave 64x64 via
// 2x2 v_mfma_f32_32x32x16_bf16.  XOR-swizzled LDS staging, single buffer.
// FLAT grid modes (XCD locality): 0 = normal 3D grid.
//   1 = flat 1D, batch = id&7 (pins batch->XCD), x = rem & ((1<<sh)-1), y = rem>>sh
//   2 = flat 1D, batch = id&7, y = rem & ((1<<sh)-1), x = rem>>sh
// LIMIT: skip row-blocks past mlim[z].  SCATTER: row -> idx[z][row], < cnt[z].
// ---------------------------------------------------------------------------
template<bool C_BF16, bool BIAS, bool LIMIT, bool SCATTER, int FLAT>
__global__ __launch_bounds__(256) void gemm_bt(
    const unsigned short* __restrict__ A, const unsigned short* __restrict__ Bt,
    void* __restrict__ Cp, const float* __restrict__ bias,
    int N, int K, long sA, long sB, long sC, float scale,
    const int* __restrict__ mlim, const int* __restrict__ cntp,
    const int* __restrict__ idx, int sh)
{
    int bx, by, bz;
    if (FLAT == 0) {
        bx = blockIdx.x; by = blockIdx.y; bz = blockIdx.z;
    } else {
        const int id = blockIdx.x;
        bz = id & 7;                       // batch -> XCD (round-robin heuristic)
        const int rem = id >> 3;
        const int m = (1 << sh) - 1;
        if (FLAT == 1) { bx = rem & m; by = rem >> sh; }
        else           { by = rem & m; bx = rem >> sh; }
    }
    const int row0 = bx * 128;
    if (LIMIT && row0 >= mlim[bz]) return;

    __shared__ unsigned short As[128 * 64];
    __shared__ unsigned short Bs[128 * 64];

    const int tid  = threadIdx.x;
    const int lane = tid & 63;
    const int wave = tid >> 6;
    const int wm   = wave >> 1;       // 0..1
    const int wn   = wave & 1;        // 0..1
    const int l31  = lane & 31;
    const int half = lane >> 5;       // 0..1
    const int x7   = lane & 7;
    const int col0 = by * 128;
    const long zA = (long)bz * sA;
    const long zB = (long)bz * sB;
    const long zC = (long)bz * sC;

    // staging: one async chunk = 1KB = 8 rows x 128B. lane i -> row sr=i>>3,
    // LDS slot i&7; global k-chunk sq = (i&7)^sr (XOR swizzle, in shorts*8)
    const int sr = lane >> 3;                  // 0..7
    const int sq = ((lane & 7) ^ sr) * 8;      // shorts

    const unsigned short* Abase = A  + zA + (long)row0 * K;
    const unsigned short* Bbase = Bt + zB + (long)col0 * K;
    const unsigned short* aptr[4];
    const unsigned short* bptr[4];
#pragma unroll
    for (int c = 0; c < 4; ++c) {
        const int r = (wave * 4 + c) * 8 + sr;   // 0..127
        aptr[c] = Abase + (long)r * K + sq;
        bptr[c] = Bbase + (long)r * K + sq;
    }

    floatx16 acc[2][2];
#pragma unroll
    for (int a = 0; a < 2; ++a)
#pragma unroll
        for (int b = 0; b < 2; ++b)
#pragma unroll
            for (int r = 0; r < 16; ++r) acc[a][b][r] = 0.f;

    // fragment row bases (shorts): row stride 64
    const int raf[2] = { (wm * 64 +  0 + l31) * 64, (wm * 64 + 32 + l31) * 64 };
    const int rbf[2] = { (wn * 64 +  0 + l31) * 64, (wn * 64 + 32 + l31) * 64 };

    for (int kt = 0; kt < K; kt += 64) {
#pragma unroll
        for (int c = 0; c < 4; ++c) {
            const int chunk = wave * 4 + c;
            async_load16(aptr[c] + kt, As + chunk * 512);
            async_load16(bptr[c] + kt, Bs + chunk * 512);
        }
        __syncthreads();

#pragma unroll
        for (int ks = 0; ks < 4; ++ks) {
            const int sw = ((ks * 2 + half) ^ x7) << 3;   // swizzled 16B slot (shorts)
            short8 af[2], bf[2];
#pragma unroll
            for (int t = 0; t < 2; ++t) {
                af[t] = *(const short8*)(As + raf[t] + sw);
                bf[t] = *(const short8*)(Bs + rbf[t] + sw);
            }
#pragma unroll
            for (int tm = 0; tm < 2; ++tm)
#pragma unroll
                for (int tn = 0; tn < 2; ++tn)
                    acc[tm][tn] = __builtin_amdgcn_mfma_f32_32x32x16_bf16(
                        af[tm], bf[tn], acc[tm][tn], 0, 0, 0);
        }
        __syncthreads();
    }

    // epilogue: 32x32 C/D layout col=lane&31, row=(reg&3)+8*(reg>>2)+4*(lane>>5)
    const int climit = SCATTER ? cntp[bz] : 0;
    const int* ridx  = SCATTER ? (idx + bz * SEQ) : (const int*)nullptr;
#pragma unroll
    for (int tn = 0; tn < 2; ++tn) {
        const int ccol = col0 + wn * 64 + tn * 32 + l31;
        float bv = 0.f;
        if (BIAS) bv = bias[ccol];
#pragma unroll
        for (int tm = 0; tm < 2; ++tm) {
            const int rbase = row0 + wm * 64 + tm * 32 + 4 * half;
#pragma unroll
            for (int r = 0; r < 16; ++r) {
                const int crow = rbase + (r & 3) + 8 * (r >> 2);
                float v = acc[tm][tn][r] * scale + bv;
                long orow = crow;
                if (SCATTER) {
                    if (crow >= climit) continue;
                    orow = ridx[crow];
                }
                const long ci = zC + orow * (long)N + ccol;
                if (C_BF16) ((unsigned short*)Cp)[ci] = f32_to_bf16(v);
                else        ((float*)Cp)[ci] = v;
            }
        }
    }
}

// ---------------------------------------------------------------------------
// in-place row softmax over 2048 bf16 scores; one block per compacted row
// ---------------------------------------------------------------------------
__global__ __launch_bounds__(256) void softmax_rows(
    unsigned short* __restrict__ S, const int* __restrict__ padcnt)
{
    const int b = blockIdx.x >> 11, rc = blockIdx.x & 2047;
    if (rc >= padcnt[b]) return;
    const long base = (long)blockIdx.x * SEQ + threadIdx.x * 8;
    const int lane = threadIdx.x & 63, wave = threadIdx.x >> 6;
    __shared__ float rbuf[8];

    short8 v = *(const short8*)(S + base);
    float x[8];
#pragma unroll
    for (int j = 0; j < 8; ++j) x[j] = bf16_to_f32((unsigned short)v[j]);

    float m = x[0];
#pragma unroll
    for (int j = 1; j < 8; ++j) m = fmaxf(m, x[j]);
    for (int o = 32; o; o >>= 1) m = fmaxf(m, __shfl_xor(m, o));
    if (lane == 0) rbuf[wave] = m;
    __syncthreads();
    m = fmaxf(fmaxf(rbuf[0], rbuf[1]), fmaxf(rbuf[2], rbuf[3]));

    float e[8], s = 0.f;
#pragma unroll
    for (int j = 0; j < 8; ++j) { e[j] = __expf(x[j] - m); s += e[j]; }
    for (int o = 32; o; o >>= 1) s += __shfl_xor(s, o);
    if (lane == 0) rbuf[4 + wave] = s;
    __syncthreads();
    s = rbuf[4] + rbuf[5] + rbuf[6] + rbuf[7];
    const float inv = 1.0f / s;

    short8 o8;
#pragma unroll
    for (int j = 0; j < 8; ++j) o8[j] = (short)f32_to_bf16(e[j] * inv);
    *(short8*)(S + base) = o8;
}

// ---------------------------------------------------------------------------
// rows with mask<=0.5: out[b,i,:] = mavg[b,:]/masked_count  (exact fp32 path)
// ---------------------------------------------------------------------------
__global__ __launch_bounds__(256) void overwrite_masked(
    float* __restrict__ out, const float* __restrict__ mask,
    const float* __restrict__ mavg, const int* __restrict__ cnt)
{
    const int bid = blockIdx.x;            // b*SEQ + i
    const int b = bid >> 11;
    if (mask[bid] > 0.5f) return;
    const float inv = 1.0f / (float)(SEQ - cnt[b]);
    const long obase = (long)bid * DIM;
    const float* mv = mavg + b * DIM;
    for (int d = threadIdx.x; d < DIM; d += 256)
        out[obase + d] = mv[d] * inv;
}

extern "C" void kernel_launch(void* const* d_in, const int* in_sizes, int n_in,
                              void* d_out, int out_size, void* d_ws, size_t ws_size,
                              hipStream_t stream) {
    (void)in_sizes; (void)n_in; (void)out_size;
    const float* input_q = (const float*)d_in[0];
    const float* input_k = (const float*)d_in[1];
    const float* k_mask  = (const float*)d_in[2];
    const float* Wq      = (const float*)d_in[3];
    const float* bq      = (const float*)d_in[4];
    const float* Wk      = (const float*)d_in[5];
    const float* bk      = (const float*)d_in[6];
    (void)bk;   // bk shifts each score row by a constant -> softmax-invariant
    float* out = (float*)d_out;

    // Workspace map (aliases sequenced by stream order):
    //   qc   aliases S lo 32MB      (dead once qpp computed, before scores writes S)
    //   Wqb/Wkb alias qpp lo 4MB    (dead once Gt computed, before qpp written)
    char* ws = (char*)d_ws;
    unsigned short* qc   = (unsigned short*)(ws);                 // 32MB
    unsigned short* S    = (unsigned short*)(ws);                 // 64MB
    unsigned short* qpp  = (unsigned short*)(ws + 67108864);      // 32MB
    unsigned short* Wqb  = (unsigned short*)(ws + 67108864);      // 2MB (alias)
    unsigned short* Wkb  = (unsigned short*)(ws + 69206016);      // 2MB (alias)
    unsigned short* kbf  = (unsigned short*)(ws + 100663296);     // 32MB
    unsigned short* Vt   = (unsigned short*)(ws + 134217728);     // 32MB
    unsigned short* Gt   = (unsigned short*)(ws + 167772160);     // 2MB
    float*          g0   = (float*)(ws + 169869312);              // 4KB
    float*          mavg = (float*)(ws + 169873408);              // 32KB
    int*            idx  = (int*)(ws + 169906176);                // 64KB
    int*            cnts = (int*)(ws + 169971712);                // 32B
    int*            pcnt = (int*)(ws + 169971744);                // 32B
    if (ws_size < 169971776) return;

    hipMemsetAsync(mavg, 0, BATCH * DIM * sizeof(float), stream);

    build_idx<<<BATCH, 256, 0, stream>>>(k_mask, idx, cnts, pcnt);
    gather_cvt_q<<<dim3(SEQ, BATCH), 256, 0, stream>>>(input_q, idx, pcnt, qc);
    prep_kv<<<dim3(DIM / 32, SEQ / 32, BATCH), 256, 0, stream>>>(input_k, k_mask, kbf, Vt, mavg);
    cvt_bf16<<<512, 256, 0, stream>>>(Wq, Wqb);
    cvt_bf16<<<512, 256, 0, stream>>>(Wk, Wkb);
    proj_bias<<<DIM, 256, 0, stream>>>(bq, Wk, g0);

    // Gt[d,e] = sum_h Wk[d,h] * Wq[e,h]   (combined projection, 1024^3)
    gemm_bt<true, false, false, false, 0><<<dim3(8, 8, 1), 256, 0, stream>>>(
        Wkb, Wqb, Gt, nullptr, DIM, DIM, 0, 0, 0, 1.0f, nullptr, nullptr, nullptr, 0);

    // q''[m,d] = sum_e qc[m,e] * Gt[d,e] + g0[d]   (compacted; batch->XCD, y-fast ny=8)
    gemm_bt<true, true, true, false, 2><<<8 * 16 * 8, 256, 0, stream>>>(
        qc, Gt, qpp, g0, DIM, DIM,
        (long)SEQ * DIM, 0, (long)SEQ * DIM, 1.0f, pcnt, nullptr, nullptr, 3);

    // scores: S[i,j] = q''[i,:] . kbf[j,:] / 32 -> bf16  (batch->XCD, x-fast nx=16)
    gemm_bt<true, false, true, false, 1><<<8 * 16 * 16, 256, 0, stream>>>(
        qpp, kbf, S, nullptr, SEQ, DIM,
        (long)SEQ * DIM, (long)SEQ * DIM, (long)SEQ * SEQ, 0.03125f, pcnt, nullptr, nullptr, 4);

    softmax_rows<<<BATCH * SEQ, 256, 0, stream>>>(S, pcnt);

    // out rows (scattered): per batch P @ V  (batch->XCD, y-fast ny=8)
    gemm_bt<false, false, true, true, 2><<<8 * 16 * 8, 256, 0, stream>>>(
        S, Vt, out, nullptr, DIM, SEQ,
        (long)SEQ * SEQ, (long)DIM * SEQ, (long)SEQ * DIM, 1.0f, pcnt, cnts, idx, 3);

    overwrite_masked<<<BATCH * SEQ, 256, 0, stream>>>(out, k_mask, mavg, cnts);
}